// Round 1
// 584.285 us; speedup vs baseline: 1.1421x; 1.1421x over previous
//
#include <hip/hip_runtime.h>
#include <hip/hip_bf16.h>
#include <cmath>

// Problem: N=64, T=512, D=256, H=256 (all fp32)
//   c   = x @ Wx + b          (N,T,H)  -- big parallel GEMM (phase 1)
//   h_t = tanh(c_t + h_{t-1} @ Wh)     -- sequential scan   (phase 2)
// Output: all h_t, (N,T,H).
//
// Phase 1 writes c directly into d_out; phase 2 updates d_out in place.
//
// Phase 2 (this round's change): 64 blocks x 1024 threads.
//   - __launch_bounds__(1024, 4): 4 waves/EU -> 128 VGPR cap, so the Wh
//     tile is truly register-resident (previous version reported 60 VGPRs,
//     i.e. the compiler targeted 2 blocks/CU and re-fetched 256KB of Wh
//     from L2 EVERY timestep: 8 GB of L2 traffic = the bottleneck).
//   - Column-blocking: thread owns 4 columns x 16 k-values (W = 16 float4
//     = 64 VGPRs). Each broadcast h value is reused across 4 columns ->
//     LDS broadcast traffic per step drops 256KB -> 64KB.

#define M_TOT 32768   // N*T
#define KDIM  256
#define HDIM  256
#define TSTEPS 512
#define NBATCH 64

// ---------------- Phase 1: c = x @ Wx + b ----------------
// 64x64 tile per block, K-chunks of 64, 256 threads, 4x4 outputs/thread.
__global__ __launch_bounds__(256) void xw_gemm(
    const float* __restrict__ x,    // (32768, 256)
    const float* __restrict__ Wx,   // (256, 256)
    const float* __restrict__ bias, // (256)
    float* __restrict__ out)        // (32768, 256)
{
    __shared__ float As[64][68];   // [row][k]  (+4 pad)
    __shared__ float Bs[64][68];   // [k][col]  (+4 pad)

    const int tid = threadIdx.x;
    const int tx = tid & 15;        // 0..15 -> 4 output cols each
    const int ty = tid >> 4;        // 0..15 -> 4 output rows each
    const int m0 = blockIdx.x * 64;
    const int n0 = blockIdx.y * 64;

    float acc[4][4];
#pragma unroll
    for (int i = 0; i < 4; ++i)
#pragma unroll
        for (int j = 0; j < 4; ++j) acc[i][j] = 0.f;

    for (int kc = 0; kc < KDIM; kc += 64) {
#pragma unroll
        for (int l = 0; l < 4; ++l) {
            int idx = tid + l * 256;          // 0..1023 float4 slots
            int row = idx >> 4;
            int c4  = (idx & 15) << 2;
            float4 va = *(const float4*)&x [(size_t)(m0 + row) * KDIM + kc + c4];
            float4 vb = *(const float4*)&Wx[(size_t)(kc + row) * HDIM + n0 + c4];
            *(float4*)&As[row][c4] = va;
            *(float4*)&Bs[row][c4] = vb;
        }
        __syncthreads();

#pragma unroll
        for (int kk = 0; kk < 64; kk += 4) {
            float4 a[4], bv[4];
#pragma unroll
            for (int i = 0; i < 4; ++i) a[i]  = *(const float4*)&As[ty * 4 + i][kk];
#pragma unroll
            for (int p = 0; p < 4; ++p) bv[p] = *(const float4*)&Bs[kk + p][tx * 4];
#pragma unroll
            for (int i = 0; i < 4; ++i) {
                acc[i][0] += a[i].x * bv[0].x + a[i].y * bv[1].x + a[i].z * bv[2].x + a[i].w * bv[3].x;
                acc[i][1] += a[i].x * bv[0].y + a[i].y * bv[1].y + a[i].z * bv[2].y + a[i].w * bv[3].y;
                acc[i][2] += a[i].x * bv[0].z + a[i].y * bv[1].z + a[i].z * bv[2].z + a[i].w * bv[3].z;
                acc[i][3] += a[i].x * bv[0].w + a[i].y * bv[1].w + a[i].z * bv[2].w + a[i].w * bv[3].w;
            }
        }
        __syncthreads();
    }

    float4 bj = *(const float4*)&bias[n0 + tx * 4];
#pragma unroll
    for (int i = 0; i < 4; ++i) {
        float4 v;
        v.x = acc[i][0] + bj.x;
        v.y = acc[i][1] + bj.y;
        v.z = acc[i][2] + bj.z;
        v.w = acc[i][3] + bj.w;
        *(float4*)&out[(size_t)(m0 + ty * 4 + i) * HDIM + n0 + tx * 4] = v;
    }
}

// ---------------- Phase 2: sequential scan ----------------
// One block per batch row. 1024 threads:
//   jq = tid & 63  -> column quad, owns columns 4*jq .. 4*jq+3
//   g  = tid >> 6  -> k-group, owns k in [16*g, 16*g+16)
// W (Wh[16g+k][4jq..4jq+3], k=0..15) persistent in 16 float4 = 64 VGPRs.
// h broadcast from LDS (4 float4 reads/thread, each reused for 4 columns).
// 16-way K partial reduction through LDS.
__global__ __launch_bounds__(1024, 4) void rnn_scan(
    const float* __restrict__ h0,   // (64, 256)
    const float* __restrict__ Wh,   // (256, 256)
    float* __restrict__ out)        // (64, 512, 256), holds c; overwritten with h
{
    const int r   = blockIdx.x;     // batch row
    const int tid = threadIdx.x;
    const int jq  = tid & 63;       // column quad index
    const int g   = tid >> 6;       // k-group (0..15)
    const int j0  = jq << 2;        // first owned column

    __shared__ float h[256];
    __shared__ float red[16][256];  // [k-group][column] partials

    // Persistent W tile: W[k] = Wh[16g+k][j0..j0+3]   (coalesced loads:
    // consecutive jq at same g read consecutive float4 of one Wh row).
    float4 W[16];
    {
        const float* wp = Wh + (size_t)(g * 16) * HDIM + j0;
#pragma unroll
        for (int k = 0; k < 16; ++k)
            W[k] = *(const float4*)(wp + (size_t)k * HDIM);
    }

    if (tid < 256) h[tid] = h0[(size_t)r * HDIM + tid];

    float* outr = out + (size_t)r * TSTEPS * HDIM;
    __syncthreads();

    for (int t = 0; t < TSTEPS; ++t) {
        // Prefetch c_t (phase-1 result); latency hidden behind the FMA phase.
        float c = 0.f;
        if (tid < 256) c = outr[(size_t)t * HDIM + tid];

        // FMA phase: acc[col] = sum_{k in group} h[16g+k] * Wh[16g+k][col]
        // All 64 lanes of a wave share g -> LDS reads are broadcasts.
        const float4* hv = (const float4*)(h + (g << 4));
        float ax = 0.f, ay = 0.f, az = 0.f, aw = 0.f;
#pragma unroll
        for (int i = 0; i < 4; ++i) {
            float4 hh = hv[i];
            ax += hh.x * W[4 * i + 0].x;
            ay += hh.x * W[4 * i + 0].y;
            az += hh.x * W[4 * i + 0].z;
            aw += hh.x * W[4 * i + 0].w;
            ax += hh.y * W[4 * i + 1].x;
            ay += hh.y * W[4 * i + 1].y;
            az += hh.y * W[4 * i + 1].z;
            aw += hh.y * W[4 * i + 1].w;
            ax += hh.z * W[4 * i + 2].x;
            ay += hh.z * W[4 * i + 2].y;
            az += hh.z * W[4 * i + 2].z;
            aw += hh.z * W[4 * i + 2].w;
            ax += hh.w * W[4 * i + 3].x;
            ay += hh.w * W[4 * i + 3].y;
            az += hh.w * W[4 * i + 3].z;
            aw += hh.w * W[4 * i + 3].w;
        }
        float4 acc; acc.x = ax; acc.y = ay; acc.z = az; acc.w = aw;
        *(float4*)&red[g][j0] = acc;   // conflict-free: consecutive float4/lane
        __syncthreads();

        if (tid < 256) {
            // Sum the 16 k-group partials for column tid.
            // red[g][tid]: lanes 0..63 -> 2 lanes/bank, conflict-free.
            float s0 = red[0][tid] + red[1][tid];
            float s1 = red[2][tid] + red[3][tid];
            float s2 = red[4][tid] + red[5][tid];
            float s3 = red[6][tid] + red[7][tid];
            float s4 = red[8][tid] + red[9][tid];
            float s5 = red[10][tid] + red[11][tid];
            float s6 = red[12][tid] + red[13][tid];
            float s7 = red[14][tid] + red[15][tid];
            float s  = (((s0 + s1) + (s2 + s3)) + ((s4 + s5) + (s6 + s7))) + c;
            float hn = tanhf(s);
            outr[(size_t)t * HDIM + tid] = hn;  // in-place: c was read above
            h[tid] = hn;                        // safe: all FMA reads done (barrier)
        }
        __syncthreads();   // next step's FMA must see updated h
    }
}

extern "C" void kernel_launch(void* const* d_in, const int* in_sizes, int n_in,
                              void* d_out, int out_size, void* d_ws, size_t ws_size,
                              hipStream_t stream) {
    const float* x  = (const float*)d_in[0];   // (64,512,256)
    const float* h0 = (const float*)d_in[1];   // (64,256)
    const float* Wx = (const float*)d_in[2];   // (256,256)
    const float* Wh = (const float*)d_in[3];   // (256,256)
    const float* b  = (const float*)d_in[4];   // (256)
    float* out = (float*)d_out;                // (64,512,256)

    // Phase 1: input projection into d_out.
    dim3 g1(M_TOT / 64, HDIM / 64);
    xw_gemm<<<g1, 256, 0, stream>>>(x, Wx, b, out);

    // Phase 2: sequential scan, in place.
    rnn_scan<<<NBATCH, 1024, 0, stream>>>(h0, Wh, out);
}

// Round 2
// 503.332 us; speedup vs baseline: 1.3258x; 1.1608x over previous
//
#include <hip/hip_runtime.h>
#include <hip/hip_bf16.h>
#include <cmath>

// Problem: N=64, T=512, D=256, H=256 (all fp32)
//   c   = x @ Wx + b          (N,T,H)  -- big parallel GEMM (phase 1)
//   h_t = tanh(c_t + h_{t-1} @ Wh)     -- sequential scan   (phase 2)
// Output: all h_t, (N,T,H).
//
// Phase 1 writes c directly into d_out; phase 2 updates d_out in place.
//
// Round-2 changes:
//  - rnn_scan: pin the 64-VGPR Wh tile with an opaque asm ("+v") so the
//    compiler cannot sink/rematerialize the loads into the timestep loop.
//    (Rounds 0/1 reported 60/48 VGPRs => W was re-fetched from L2 every
//    step: 64 CU x 512 steps x 256KB = 8GB of L2 traffic, ~1100 cy/step.)
//  - xw_gemm: 128x128 tile, 8x8 per thread, A staged k-major in LDS.
//    Old 4x4 tile was LDS-pipe-bound (8 b128 reads per 64 FMAs); new
//    shape is 4 b128 per 128 FMAs -> VALU-bound.

#define M_TOT 32768   // N*T
#define KDIM  256
#define HDIM  256
#define TSTEPS 512
#define NBATCH 64

// ---------------- Phase 1: c = x @ Wx + b ----------------
// 128x128 tile per block, K-chunks of 32, 256 threads, 8x8 outputs/thread.
// As is stored TRANSPOSED ([k][m]) so the a-fragment is 2 float4 reads.
__global__ __launch_bounds__(256, 4) void xw_gemm(
    const float* __restrict__ x,    // (32768, 256)
    const float* __restrict__ Wx,   // (256, 256)
    const float* __restrict__ bias, // (256)
    float* __restrict__ out)        // (32768, 256)
{
    __shared__ float As[32][132];   // [k][m] (+4 pad; 528B row stride, 16B-aligned)
    __shared__ float Bs[32][132];   // [k][n] (+4 pad)

    const int tid = threadIdx.x;
    const int tx = tid & 15;        // 0..15 -> 8 output cols each
    const int ty = tid >> 4;        // 0..15 -> 8 output rows each
    const int m0 = blockIdx.x * 128;
    const int n0 = blockIdx.y * 128;

    float acc[8][8];
#pragma unroll
    for (int i = 0; i < 8; ++i)
#pragma unroll
        for (int j = 0; j < 8; ++j) acc[i][j] = 0.f;

    for (int kc = 0; kc < KDIM; kc += 32) {
        // Stage A (128 rows x 32 k) transposed, B (32 k x 128 cols) direct.
        // 1024 float4 slots each; 4 per thread. Global reads fully coalesced.
#pragma unroll
        for (int l = 0; l < 4; ++l) {
            int idx  = tid + l * 256;
            int arow = idx >> 3;            // 0..127 (m)
            int ac4  = (idx & 7) << 2;      // 0..28  (k)
            float4 va = *(const float4*)&x[(size_t)(m0 + arow) * KDIM + kc + ac4];
            As[ac4 + 0][arow] = va.x;
            As[ac4 + 1][arow] = va.y;
            As[ac4 + 2][arow] = va.z;
            As[ac4 + 3][arow] = va.w;
            int brow = idx >> 5;            // 0..31  (k)
            int bc4  = (idx & 31) << 2;     // 0..124 (n)
            float4 vb = *(const float4*)&Wx[(size_t)(kc + brow) * HDIM + n0 + bc4];
            *(float4*)&Bs[brow][bc4] = vb;
        }
        __syncthreads();

#pragma unroll
        for (int kk = 0; kk < 32; ++kk) {
            float4 a0 = *(const float4*)&As[kk][ty * 8];
            float4 a1 = *(const float4*)&As[kk][ty * 8 + 4];
            float4 b0 = *(const float4*)&Bs[kk][tx * 8];
            float4 b1 = *(const float4*)&Bs[kk][tx * 8 + 4];
            float a[8] = {a0.x, a0.y, a0.z, a0.w, a1.x, a1.y, a1.z, a1.w};
            float b[8] = {b0.x, b0.y, b0.z, b0.w, b1.x, b1.y, b1.z, b1.w};
#pragma unroll
            for (int i = 0; i < 8; ++i)
#pragma unroll
                for (int j = 0; j < 8; ++j)
                    acc[i][j] += a[i] * b[j];
        }
        __syncthreads();
    }

    float4 bj0 = *(const float4*)&bias[n0 + tx * 8];
    float4 bj1 = *(const float4*)&bias[n0 + tx * 8 + 4];
#pragma unroll
    for (int i = 0; i < 8; ++i) {
        float* op = &out[(size_t)(m0 + ty * 8 + i) * HDIM + n0 + tx * 8];
        float4 v0, v1;
        v0.x = acc[i][0] + bj0.x;  v0.y = acc[i][1] + bj0.y;
        v0.z = acc[i][2] + bj0.z;  v0.w = acc[i][3] + bj0.w;
        v1.x = acc[i][4] + bj1.x;  v1.y = acc[i][5] + bj1.y;
        v1.z = acc[i][6] + bj1.z;  v1.w = acc[i][7] + bj1.w;
        *(float4*)op       = v0;
        *(float4*)(op + 4) = v1;
    }
}

// ---------------- Phase 2: sequential scan ----------------
// One block per batch row. 1024 threads:
//   jq = tid & 63  -> column quad, owns columns 4*jq .. 4*jq+3
//   g  = tid >> 6  -> k-group, owns k in [16*g, 16*g+16)
// W (Wh[16g+k][4jq..4jq+3], k=0..15) persistent in 16 float4 = 64 VGPRs,
// PINNED via opaque asm so the compiler cannot sink the loads into the loop.
// h broadcast from LDS (4 float4 reads/thread, each reused for 4 columns).
// 16-way K partial reduction through LDS.
__global__ __launch_bounds__(1024, 4) void rnn_scan(
    const float* __restrict__ h0,   // (64, 256)
    const float* __restrict__ Wh,   // (256, 256)
    float* __restrict__ out)        // (64, 512, 256), holds c; overwritten with h
{
    const int r   = blockIdx.x;     // batch row
    const int tid = threadIdx.x;
    const int jq  = tid & 63;       // column quad index
    const int g   = tid >> 6;       // k-group (0..15)
    const int j0  = jq << 2;        // first owned column

    __shared__ float h[256];
    __shared__ float red[16][256];  // [k-group][column] partials

    // Persistent W tile: W[k] = Wh[16g+k][j0..j0+3]   (coalesced loads:
    // consecutive jq at same g read consecutive float4 of one Wh row).
    float4 W[16];
    {
        const float* wp = Wh + (size_t)(g * 16) * HDIM + j0;
#pragma unroll
        for (int k = 0; k < 16; ++k)
            W[k] = *(const float4*)(wp + (size_t)k * HDIM);
    }
    // PIN: opaque read-write asm on every component. The loads above feed a
    // volatile asm whose outputs feed the loop -> the compiler can neither
    // sink nor rematerialize them; W stays in 64 VGPRs for all 512 steps.
#pragma unroll
    for (int k = 0; k < 16; ++k)
        asm volatile("" : "+v"(W[k].x), "+v"(W[k].y), "+v"(W[k].z), "+v"(W[k].w));

    if (tid < 256) h[tid] = h0[(size_t)r * HDIM + tid];

    float* outr = out + (size_t)r * TSTEPS * HDIM;
    __syncthreads();

    for (int t = 0; t < TSTEPS; ++t) {
        // Prefetch c_t (phase-1 result); latency hidden behind the FMA phase.
        float c = 0.f;
        if (tid < 256) c = outr[(size_t)t * HDIM + tid];

        // FMA phase: acc[col] = sum_{k in group} h[16g+k] * Wh[16g+k][col]
        // All 64 lanes of a wave share g -> LDS reads are broadcasts.
        const float4* hv = (const float4*)(h + (g << 4));
        float ax = 0.f, ay = 0.f, az = 0.f, aw = 0.f;
#pragma unroll
        for (int i = 0; i < 4; ++i) {
            float4 hh = hv[i];
            ax += hh.x * W[4 * i + 0].x;
            ay += hh.x * W[4 * i + 0].y;
            az += hh.x * W[4 * i + 0].z;
            aw += hh.x * W[4 * i + 0].w;
            ax += hh.y * W[4 * i + 1].x;
            ay += hh.y * W[4 * i + 1].y;
            az += hh.y * W[4 * i + 1].z;
            aw += hh.y * W[4 * i + 1].w;
            ax += hh.z * W[4 * i + 2].x;
            ay += hh.z * W[4 * i + 2].y;
            az += hh.z * W[4 * i + 2].z;
            aw += hh.z * W[4 * i + 2].w;
            ax += hh.w * W[4 * i + 3].x;
            ay += hh.w * W[4 * i + 3].y;
            az += hh.w * W[4 * i + 3].z;
            aw += hh.w * W[4 * i + 3].w;
        }
        float4 acc; acc.x = ax; acc.y = ay; acc.z = az; acc.w = aw;
        *(float4*)&red[g][j0] = acc;   // conflict-free: consecutive float4/lane
        __syncthreads();

        if (tid < 256) {
            // Sum the 16 k-group partials for column tid.
            // red[g][tid]: lanes 0..63 -> 2 lanes/bank, conflict-free.
            float s0 = red[0][tid] + red[1][tid];
            float s1 = red[2][tid] + red[3][tid];
            float s2 = red[4][tid] + red[5][tid];
            float s3 = red[6][tid] + red[7][tid];
            float s4 = red[8][tid] + red[9][tid];
            float s5 = red[10][tid] + red[11][tid];
            float s6 = red[12][tid] + red[13][tid];
            float s7 = red[14][tid] + red[15][tid];
            float s  = (((s0 + s1) + (s2 + s3)) + ((s4 + s5) + (s6 + s7))) + c;
            float hn = tanhf(s);
            outr[(size_t)t * HDIM + tid] = hn;  // in-place: c was read above
            h[tid] = hn;                        // safe: all FMA reads done (barrier)
        }
        __syncthreads();   // next step's FMA must see updated h
    }
}

extern "C" void kernel_launch(void* const* d_in, const int* in_sizes, int n_in,
                              void* d_out, int out_size, void* d_ws, size_t ws_size,
                              hipStream_t stream) {
    const float* x  = (const float*)d_in[0];   // (64,512,256)
    const float* h0 = (const float*)d_in[1];   // (64,256)
    const float* Wx = (const float*)d_in[2];   // (256,256)
    const float* Wh = (const float*)d_in[3];   // (256,256)
    const float* b  = (const float*)d_in[4];   // (256)
    float* out = (float*)d_out;                // (64,512,256)

    // Phase 1: input projection into d_out.
    dim3 g1(M_TOT / 128, HDIM / 128);
    xw_gemm<<<g1, 256, 0, stream>>>(x, Wx, b, out);

    // Phase 2: sequential scan, in place.
    rnn_scan<<<NBATCH, 1024, 0, stream>>>(h0, Wh, out);
}

// Round 3
// 478.964 us; speedup vs baseline: 1.3932x; 1.0509x over previous
//
#include <hip/hip_runtime.h>
#include <hip/hip_bf16.h>
#include <cmath>

// Problem: N=64, T=512, D=256, H=256 (all fp32)
//   c   = x @ Wx + b          (N,T,H)  -- big parallel GEMM (phase 1)
//   h_t = tanh(c_t + h_{t-1} @ Wh)     -- sequential scan   (phase 2)
// Output: all h_t, (N,T,H).
//
// Phase 1 writes c directly into d_out; phase 2 updates d_out in place.
//
// Round-3 changes:
//  - rnn_scan: amdgpu_waves_per_eu(4,4). Rounds 0-2 showed the allocator
//    targets ~10 waves/SIMD (48 VGPR) and sinks/spills the 64-float Wh
//    tile no matter what hints we give from below; capping MAX waves/EU
//    at 4 makes the 128-VGPR budget free, so W stays resident. asm pin
//    kept (forbids remat of the loads).
//  - rnn_scan: c_t prefetched one FULL step ahead (c_next double buffer).
//    c comes from L2/L3/HBM (~300-900 cy); the old same-iteration
//    prefetch only hid ~512 cy.
//  - xw_gemm: 128x64 tiles -> grid 1024 = 4 blocks/CU (was 512 = 2/CU);
//    16 waves/CU for latency hiding.

#define M_TOT 32768   // N*T
#define KDIM  256
#define HDIM  256
#define TSTEPS 512
#define NBATCH 64

// ---------------- Phase 1: c = x @ Wx + b ----------------
// 128x64 tile per block, K-chunks of 32, 256 threads, 8x4 outputs/thread.
// As is stored TRANSPOSED ([k][m]) so the a-fragment is 2 float4 reads.
__global__ __launch_bounds__(256, 4) void xw_gemm(
    const float* __restrict__ x,    // (32768, 256)
    const float* __restrict__ Wx,   // (256, 256)
    const float* __restrict__ bias, // (256)
    float* __restrict__ out)        // (32768, 256)
{
    __shared__ float As[32][132];   // [k][m] (+4 pad; rows 16B-aligned)
    __shared__ float Bs[32][68];    // [k][n] (+4 pad)

    const int tid = threadIdx.x;
    const int tx = tid & 15;        // 0..15 -> 4 output cols each
    const int ty = tid >> 4;        // 0..15 -> 8 output rows each
    const int m0 = blockIdx.x * 128;
    const int n0 = blockIdx.y * 64;

    float acc[8][4];
#pragma unroll
    for (int i = 0; i < 8; ++i)
#pragma unroll
        for (int j = 0; j < 4; ++j) acc[i][j] = 0.f;

    for (int kc = 0; kc < KDIM; kc += 32) {
        // Stage A (128 m x 32 k) transposed: 1024 float4 slots, 4/thread.
#pragma unroll
        for (int l = 0; l < 4; ++l) {
            int idx  = tid + l * 256;
            int arow = idx >> 3;            // 0..127 (m)
            int ac4  = (idx & 7) << 2;      // 0..28  (k)
            float4 va = *(const float4*)&x[(size_t)(m0 + arow) * KDIM + kc + ac4];
            As[ac4 + 0][arow] = va.x;
            As[ac4 + 1][arow] = va.y;
            As[ac4 + 2][arow] = va.z;
            As[ac4 + 3][arow] = va.w;
        }
        // Stage B (32 k x 64 n): 512 float4 slots, 2/thread.
#pragma unroll
        for (int l = 0; l < 2; ++l) {
            int idx  = tid + l * 256;
            int brow = idx >> 4;            // 0..31 (k)
            int bc4  = (idx & 15) << 2;     // 0..60 (n)
            float4 vb = *(const float4*)&Wx[(size_t)(kc + brow) * HDIM + n0 + bc4];
            *(float4*)&Bs[brow][bc4] = vb;
        }
        __syncthreads();

#pragma unroll
        for (int kk = 0; kk < 32; ++kk) {
            float4 a0 = *(const float4*)&As[kk][ty * 8];
            float4 a1 = *(const float4*)&As[kk][ty * 8 + 4];
            float4 b0 = *(const float4*)&Bs[kk][tx * 4];
            float a[8] = {a0.x, a0.y, a0.z, a0.w, a1.x, a1.y, a1.z, a1.w};
            float b[4] = {b0.x, b0.y, b0.z, b0.w};
#pragma unroll
            for (int i = 0; i < 8; ++i)
#pragma unroll
                for (int j = 0; j < 4; ++j)
                    acc[i][j] += a[i] * b[j];
        }
        __syncthreads();
    }

    float4 bj = *(const float4*)&bias[n0 + tx * 4];
#pragma unroll
    for (int i = 0; i < 8; ++i) {
        float4 v;
        v.x = acc[i][0] + bj.x;
        v.y = acc[i][1] + bj.y;
        v.z = acc[i][2] + bj.z;
        v.w = acc[i][3] + bj.w;
        *(float4*)&out[(size_t)(m0 + ty * 8 + i) * HDIM + n0 + tx * 4] = v;
    }
}

// ---------------- Phase 2: sequential scan ----------------
// One block per batch row. 1024 threads:
//   jq = tid & 63  -> column quad, owns columns 4*jq .. 4*jq+3
//   g  = tid >> 6  -> k-group, owns k in [16*g, 16*g+16)
// W (Wh[16g+k][4jq..4jq+3], k=0..15) persistent in 16 float4 = 64 VGPRs.
// waves_per_eu(4,4): occupancy capped at 1 block/CU -> the 128-VGPR
// budget is free -> allocator has no incentive to spill/sink W.
// h broadcast from LDS (4 float4 reads/thread, each reused for 4 columns).
// 16-way K partial reduction through LDS. c prefetched one step ahead.
__global__ __launch_bounds__(1024)
__attribute__((amdgpu_waves_per_eu(4, 4)))
void rnn_scan(
    const float* __restrict__ h0,   // (64, 256)
    const float* __restrict__ Wh,   // (256, 256)
    float* __restrict__ out)        // (64, 512, 256), holds c; overwritten with h
{
    const int r   = blockIdx.x;     // batch row
    const int tid = threadIdx.x;
    const int jq  = tid & 63;       // column quad index
    const int g   = tid >> 6;       // k-group (0..15)
    const int j0  = jq << 2;        // first owned column

    __shared__ float h[256];
    __shared__ float red[16][256];  // [k-group][column] partials

    // Persistent W tile: W[k] = Wh[16g+k][j0..j0+3]   (coalesced loads:
    // consecutive jq at same g read consecutive float4 of one Wh row).
    float4 W[16];
    {
        const float* wp = Wh + (size_t)(g * 16) * HDIM + j0;
#pragma unroll
        for (int k = 0; k < 16; ++k)
            W[k] = *(const float4*)(wp + (size_t)k * HDIM);
    }
    // PIN: opaque read-write asm on every component -> loads cannot be
    // rematerialized inside the loop.
#pragma unroll
    for (int k = 0; k < 16; ++k)
        asm volatile("" : "+v"(W[k].x), "+v"(W[k].y), "+v"(W[k].z), "+v"(W[k].w));

    if (tid < 256) h[tid] = h0[(size_t)r * HDIM + tid];

    float* outr = out + (size_t)r * TSTEPS * HDIM;

    // Prefetch c_0 a full step early.
    float c_next = 0.f;
    if (g < 4) c_next = outr[tid];   // tid<256 <=> g<4 (wave-uniform branch)

    __syncthreads();

    for (int t = 0; t < TSTEPS; ++t) {
        float c = c_next;
        // Prefetch c_{t+1}: a full step (~1000 cy) to cover L2/L3/HBM.
        if (g < 4) {
            int tn = (t + 1 < TSTEPS) ? (t + 1) : t;   // clamp; value unused at t=511
            c_next = outr[(size_t)tn * HDIM + tid];
        }

        // FMA phase: acc[col] = sum_{k in group} h[16g+k] * Wh[16g+k][col]
        // All 64 lanes of a wave share g -> LDS reads are broadcasts.
        const float4* hv = (const float4*)(h + (g << 4));
        float ax = 0.f, ay = 0.f, az = 0.f, aw = 0.f;
#pragma unroll
        for (int i = 0; i < 4; ++i) {
            float4 hh = hv[i];
            ax += hh.x * W[4 * i + 0].x;
            ay += hh.x * W[4 * i + 0].y;
            az += hh.x * W[4 * i + 0].z;
            aw += hh.x * W[4 * i + 0].w;
            ax += hh.y * W[4 * i + 1].x;
            ay += hh.y * W[4 * i + 1].y;
            az += hh.y * W[4 * i + 1].z;
            aw += hh.y * W[4 * i + 1].w;
            ax += hh.z * W[4 * i + 2].x;
            ay += hh.z * W[4 * i + 2].y;
            az += hh.z * W[4 * i + 2].z;
            aw += hh.z * W[4 * i + 2].w;
            ax += hh.w * W[4 * i + 3].x;
            ay += hh.w * W[4 * i + 3].y;
            az += hh.w * W[4 * i + 3].z;
            aw += hh.w * W[4 * i + 3].w;
        }
        float4 acc; acc.x = ax; acc.y = ay; acc.z = az; acc.w = aw;
        *(float4*)&red[g][j0] = acc;   // conflict-free: consecutive float4/lane
        __syncthreads();

        if (tid < 256) {
            // Sum the 16 k-group partials for column tid.
            float s0 = red[0][tid] + red[1][tid];
            float s1 = red[2][tid] + red[3][tid];
            float s2 = red[4][tid] + red[5][tid];
            float s3 = red[6][tid] + red[7][tid];
            float s4 = red[8][tid] + red[9][tid];
            float s5 = red[10][tid] + red[11][tid];
            float s6 = red[12][tid] + red[13][tid];
            float s7 = red[14][tid] + red[15][tid];
            float s  = (((s0 + s1) + (s2 + s3)) + ((s4 + s5) + (s6 + s7))) + c;
            float hn = tanhf(s);
            outr[(size_t)t * HDIM + tid] = hn;  // in-place: c was read above
            h[tid] = hn;                        // safe: all FMA reads done (barrier)
        }
        __syncthreads();   // next step's FMA must see updated h
    }
}

extern "C" void kernel_launch(void* const* d_in, const int* in_sizes, int n_in,
                              void* d_out, int out_size, void* d_ws, size_t ws_size,
                              hipStream_t stream) {
    const float* x  = (const float*)d_in[0];   // (64,512,256)
    const float* h0 = (const float*)d_in[1];   // (64,256)
    const float* Wx = (const float*)d_in[2];   // (256,256)
    const float* Wh = (const float*)d_in[3];   // (256,256)
    const float* b  = (const float*)d_in[4];   // (256)
    float* out = (float*)d_out;                // (64,512,256)

    // Phase 1: input projection into d_out.
    dim3 g1(M_TOT / 128, HDIM / 64);
    xw_gemm<<<g1, 256, 0, stream>>>(x, Wx, b, out);

    // Phase 2: sequential scan, in place.
    rnn_scan<<<NBATCH, 1024, 0, stream>>>(h0, Wh, out);
}

// Round 4
// 478.530 us; speedup vs baseline: 1.3945x; 1.0009x over previous
//
#include <hip/hip_runtime.h>
#include <hip/hip_bf16.h>
#include <cmath>

// Problem: N=64, T=512, D=256, H=256 (all fp32)
//   c   = x @ Wx + b          (N,T,H)  -- big parallel GEMM (phase 1)
//   h_t = tanh(c_t + h_{t-1} @ Wh)     -- sequential scan   (phase 2)
// Output: all h_t, (N,T,H).
//
// Phase 1 writes c directly into d_out; phase 2 updates d_out in place.
//
// Round-4 changes:
//  - rnn_scan: amdgpu_num_vgpr(128). Rounds 0-3 proved the allocator
//    spills the 64-float Wh tile no matter what occupancy HINTS we give
//    (VGPR_Count 60/48/48/52); num_vgpr sets the budget directly, so
//    the ~100-reg pressure with W resident fits without spilling.
//    W flattened to scalar float[64] (no aggregate/SROA ambiguity).
//  - xw_gemm: issue-early prefetch (load K-chunk k+1 into registers
//    right after the barrier, consume after the compute loop) so the
//    ~300-900 cy global-load latency per chunk is hidden behind the
//    ~2000 cy compute phase. launch_bounds(256,2) for the +24 regs.

#define M_TOT 32768   // N*T
#define KDIM  256
#define HDIM  256
#define TSTEPS 512
#define NBATCH 64

// ---------------- Phase 1: c = x @ Wx + b ----------------
// 128x64 tile per block, K-chunks of 32, 256 threads, 8x4 outputs/thread.
// As is stored TRANSPOSED ([k][m]) so the a-fragment is 2 float4 reads.
// Next chunk's global loads are issued before the compute loop (T14).
__global__ __launch_bounds__(256, 2) void xw_gemm(
    const float* __restrict__ x,    // (32768, 256)
    const float* __restrict__ Wx,   // (256, 256)
    const float* __restrict__ bias, // (256)
    float* __restrict__ out)        // (32768, 256)
{
    __shared__ float As[32][132];   // [k][m] (+4 pad; rows 16B-aligned)
    __shared__ float Bs[32][68];    // [k][n] (+4 pad)

    const int tid = threadIdx.x;
    const int tx = tid & 15;        // 0..15 -> 4 output cols each
    const int ty = tid >> 4;        // 0..15 -> 8 output rows each
    const int m0 = blockIdx.x * 128;
    const int n0 = blockIdx.y * 64;

    // Per-thread staging slots (addressing fixed across chunks).
    const int arow = tid >> 1;                 // 0..127 (m)   [2 slots/thread]
    const int ac4a = (tid & 1) << 3;           // 0 or 8       (k, two float4)
    const int brow = tid >> 4;                 // 0..15 (k)    [2 rows/thread]
    const int bc4  = (tid & 15) << 2;          // 0..60 (n)

    float acc[8][4];
#pragma unroll
    for (int i = 0; i < 8; ++i)
#pragma unroll
        for (int j = 0; j < 4; ++j) acc[i][j] = 0.f;

    float4 va0, va1, va2, va3, vb0, vb1;
    // Preload chunk 0.
    {
        const float* xp = &x[(size_t)(m0 + arow) * KDIM];
        va0 = *(const float4*)(xp + ac4a);
        va1 = *(const float4*)(xp + ac4a + 4);
        va2 = *(const float4*)(xp + 16 + ac4a);       // same row, k 16..31
        va3 = *(const float4*)(xp + 16 + ac4a + 4);
        vb0 = *(const float4*)&Wx[(size_t)brow * HDIM + n0 + bc4];
        vb1 = *(const float4*)&Wx[(size_t)(brow + 16) * HDIM + n0 + bc4];
    }

    for (int kc = 0; kc < KDIM; kc += 32) {
        // Write staged registers to LDS (A transposed).
        int k0 = ac4a;
        As[k0 + 0][arow] = va0.x;  As[k0 + 1][arow] = va0.y;
        As[k0 + 2][arow] = va0.z;  As[k0 + 3][arow] = va0.w;
        As[k0 + 4][arow] = va1.x;  As[k0 + 5][arow] = va1.y;
        As[k0 + 6][arow] = va1.z;  As[k0 + 7][arow] = va1.w;
        As[k0 + 16][arow] = va2.x; As[k0 + 17][arow] = va2.y;
        As[k0 + 18][arow] = va2.z; As[k0 + 19][arow] = va2.w;
        As[k0 + 20][arow] = va3.x; As[k0 + 21][arow] = va3.y;
        As[k0 + 22][arow] = va3.z; As[k0 + 23][arow] = va3.w;
        *(float4*)&Bs[brow][bc4]      = vb0;
        *(float4*)&Bs[brow + 16][bc4] = vb1;
        __syncthreads();

        // Issue next chunk's loads now; consumed after compute (latency hidden).
        if (kc + 32 < KDIM) {
            const float* xp = &x[(size_t)(m0 + arow) * KDIM + kc + 32];
            va0 = *(const float4*)(xp + ac4a);
            va1 = *(const float4*)(xp + ac4a + 4);
            va2 = *(const float4*)(xp + 16 + ac4a);
            va3 = *(const float4*)(xp + 16 + ac4a + 4);
            vb0 = *(const float4*)&Wx[(size_t)(kc + 32 + brow) * HDIM + n0 + bc4];
            vb1 = *(const float4*)&Wx[(size_t)(kc + 32 + brow + 16) * HDIM + n0 + bc4];
        }

#pragma unroll
        for (int kk = 0; kk < 32; ++kk) {
            float4 a0 = *(const float4*)&As[kk][ty * 8];
            float4 a1 = *(const float4*)&As[kk][ty * 8 + 4];
            float4 b0 = *(const float4*)&Bs[kk][tx * 4];
            float a[8] = {a0.x, a0.y, a0.z, a0.w, a1.x, a1.y, a1.z, a1.w};
            float b[4] = {b0.x, b0.y, b0.z, b0.w};
#pragma unroll
            for (int i = 0; i < 8; ++i)
#pragma unroll
                for (int j = 0; j < 4; ++j)
                    acc[i][j] += a[i] * b[j];
        }
        __syncthreads();
    }

    float4 bj = *(const float4*)&bias[n0 + tx * 4];
#pragma unroll
    for (int i = 0; i < 8; ++i) {
        float4 v;
        v.x = acc[i][0] + bj.x;
        v.y = acc[i][1] + bj.y;
        v.z = acc[i][2] + bj.z;
        v.w = acc[i][3] + bj.w;
        *(float4*)&out[(size_t)(m0 + ty * 8 + i) * HDIM + n0 + tx * 4] = v;
    }
}

// ---------------- Phase 2: sequential scan ----------------
// One block per batch row. 1024 threads:
//   jq = tid & 63  -> column quad, owns columns 4*jq .. 4*jq+3
//   g  = tid >> 6  -> k-group, owns k in [16*g, 16*g+16)
// W (Wh[16g+k][4jq..4jq+3], k=0..15) persistent in 64 VGPRs.
// amdgpu_num_vgpr(128): direct register budget (occupancy hints from
// below were ignored by the allocator for 4 straight rounds -> spill).
// h broadcast from LDS (4 float4 reads/thread, each reused for 4 columns).
// 16-way K partial reduction through LDS. c prefetched one step ahead.
__global__ __launch_bounds__(1024)
__attribute__((amdgpu_waves_per_eu(4, 4), amdgpu_num_vgpr(128)))
void rnn_scan(
    const float* __restrict__ h0,   // (64, 256)
    const float* __restrict__ Wh,   // (256, 256)
    float* __restrict__ out)        // (64, 512, 256), holds c; overwritten with h
{
    const int r   = blockIdx.x;     // batch row
    const int tid = threadIdx.x;
    const int jq  = tid & 63;       // column quad index
    const int g   = tid >> 6;       // k-group (0..15)
    const int j0  = jq << 2;        // first owned column

    __shared__ float h[256];
    __shared__ float red[16][256];  // [k-group][column] partials

    // Persistent W tile, flat scalar array:
    //   W[4k+q] = Wh[16g+k][j0+q]
    float W[64];
    {
        const float* wp = Wh + (size_t)(g * 16) * HDIM + j0;
#pragma unroll
        for (int k = 0; k < 16; ++k) {
            float4 t = *(const float4*)(wp + (size_t)k * HDIM);
            W[4 * k + 0] = t.x;
            W[4 * k + 1] = t.y;
            W[4 * k + 2] = t.z;
            W[4 * k + 3] = t.w;
        }
    }
    // PIN: opaque read-write asm -> the loads cannot be rematerialized
    // inside the loop; with the 128-reg budget they need not be spilled.
#pragma unroll
    for (int k = 0; k < 64; k += 4)
        asm volatile("" : "+v"(W[k]), "+v"(W[k + 1]), "+v"(W[k + 2]), "+v"(W[k + 3]));

    if (tid < 256) h[tid] = h0[(size_t)r * HDIM + tid];

    float* outr = out + (size_t)r * TSTEPS * HDIM;

    // Prefetch c_0 a full step early.
    float c_next = 0.f;
    if (g < 4) c_next = outr[tid];   // tid<256 <=> g<4 (wave-uniform branch)

    __syncthreads();

    for (int t = 0; t < TSTEPS; ++t) {
        float c = c_next;
        // Prefetch c_{t+1}: a full step (~1000 cy) to cover L2/L3/HBM.
        if (g < 4) {
            int tn = (t + 1 < TSTEPS) ? (t + 1) : t;   // clamp; value unused at t=511
            c_next = outr[(size_t)tn * HDIM + tid];
        }

        // FMA phase: acc[q] = sum_{k in group} h[16g+k] * Wh[16g+k][j0+q]
        // All 64 lanes of a wave share g -> LDS reads are broadcasts.
        const float4* hv = (const float4*)(h + (g << 4));
        float ax = 0.f, ay = 0.f, az = 0.f, aw = 0.f;
#pragma unroll
        for (int i = 0; i < 4; ++i) {
            float4 hh = hv[i];
            ax += hh.x * W[16 * i + 0];
            ay += hh.x * W[16 * i + 1];
            az += hh.x * W[16 * i + 2];
            aw += hh.x * W[16 * i + 3];
            ax += hh.y * W[16 * i + 4];
            ay += hh.y * W[16 * i + 5];
            az += hh.y * W[16 * i + 6];
            aw += hh.y * W[16 * i + 7];
            ax += hh.z * W[16 * i + 8];
            ay += hh.z * W[16 * i + 9];
            az += hh.z * W[16 * i + 10];
            aw += hh.z * W[16 * i + 11];
            ax += hh.w * W[16 * i + 12];
            ay += hh.w * W[16 * i + 13];
            az += hh.w * W[16 * i + 14];
            aw += hh.w * W[16 * i + 15];
        }
        float4 acc; acc.x = ax; acc.y = ay; acc.z = az; acc.w = aw;
        *(float4*)&red[g][j0] = acc;   // conflict-free: consecutive float4/lane
        __syncthreads();

        if (tid < 256) {
            // Sum the 16 k-group partials for column tid.
            float s0 = red[0][tid] + red[1][tid];
            float s1 = red[2][tid] + red[3][tid];
            float s2 = red[4][tid] + red[5][tid];
            float s3 = red[6][tid] + red[7][tid];
            float s4 = red[8][tid] + red[9][tid];
            float s5 = red[10][tid] + red[11][tid];
            float s6 = red[12][tid] + red[13][tid];
            float s7 = red[14][tid] + red[15][tid];
            float s  = (((s0 + s1) + (s2 + s3)) + ((s4 + s5) + (s6 + s7))) + c;
            float hn = tanhf(s);
            outr[(size_t)t * HDIM + tid] = hn;  // in-place: c was read above
            h[tid] = hn;                        // safe: all FMA reads done (barrier)
        }
        __syncthreads();   // next step's FMA must see updated h
    }
}

extern "C" void kernel_launch(void* const* d_in, const int* in_sizes, int n_in,
                              void* d_out, int out_size, void* d_ws, size_t ws_size,
                              hipStream_t stream) {
    const float* x  = (const float*)d_in[0];   // (64,512,256)
    const float* h0 = (const float*)d_in[1];   // (64,256)
    const float* Wx = (const float*)d_in[2];   // (256,256)
    const float* Wh = (const float*)d_in[3];   // (256,256)
    const float* b  = (const float*)d_in[4];   // (256)
    float* out = (float*)d_out;                // (64,512,256)

    // Phase 1: input projection into d_out.
    dim3 g1(M_TOT / 128, HDIM / 64);
    xw_gemm<<<g1, 256, 0, stream>>>(x, Wx, b, out);

    // Phase 2: sequential scan, in place.
    rnn_scan<<<NBATCH, 1024, 0, stream>>>(h0, Wh, out);
}